// Round 10
// baseline (22268.260 us; speedup 1.0000x reference)
//
#include <hip/hip_runtime.h>
#include <math.h>

// Problem constants (fixed by setup_inputs)
#define BB  64      // batch
#define TT  512     // seq len
#define HH  512     // hidden
#define RR  1024    // decode rows = B*S
#define HOR 64      // horizon
#define WST 520     // encoder LDS weight row stride (floats)

// encoder geometry
#define ENW 128     // encoder WGs (each owns 4 hcols)
#define ENT 1024    // encoder threads/WG

// decoder GEMM tile
#define DM 64       // rows per WG tile
#define DN 128      // gate-cols per WG tile (32 hcols x 4 gates)
#define DK 64       // k tile
#define LSTR 68     // LDS tile row stride (floats): 16B-aligned

// Persistent state in device globals (re-initialized every launch)
__device__ float g_h0[2][BB][HH];
__device__ float g_h1[2][BB][HH];
__device__ float g_c0[BB][HH];
__device__ float g_c1[BB][HH];
__device__ float g_H0[2][RR][HH];
__device__ float g_H1[2][RR][HH];
__device__ float g_C0[RR][HH];
__device__ float g_C1[RR][HH];
__device__ float g_u[2][RR];   // u double-buffer: g_u[d&1] feeds step d

__device__ __forceinline__ float sigf(float v) { return 1.0f / (1.0f + expf(-v)); }

__device__ __forceinline__ float cellupd(float iv, float fv, float gv, float ov, float& c) {
  c = sigf(fv) * c + sigf(iv) * tanhf(gv);
  return sigf(ov) * tanhf(c);
}

// ---- Tree grid barrier (encoder only). Arrival: per-WG slot store (own
// cacheline); WG0 lanes poll slots in parallel, then one flag store; others
// spin on flag. SAFETY (R2/R4 hangs): 108KB LDS -> 1 WG/CU; 128 WGs vs 256
// CUs = 2x co-residency slack. Keep it so.
__device__ __forceinline__ void gridbar(unsigned* ws, unsigned& p) {
  __syncthreads();
  ++p;
  const int tid = threadIdx.x;
  unsigned* flag = ws + ENW * 32 + 32;
  if (blockIdx.x == 0) {
    if (tid == 0)
      __hip_atomic_store(ws, p, __ATOMIC_RELEASE, __HIP_MEMORY_SCOPE_AGENT);
    if (tid < ENW) {
      while (__hip_atomic_load(ws + tid * 32, __ATOMIC_ACQUIRE,
                               __HIP_MEMORY_SCOPE_AGENT) < p)
        __builtin_amdgcn_s_sleep(1);
    }
    __syncthreads();
    if (tid == 0)
      __hip_atomic_store(flag, p, __ATOMIC_RELEASE, __HIP_MEMORY_SCOPE_AGENT);
  } else {
    if (tid == 0) {
      __hip_atomic_store(ws + blockIdx.x * 32, p, __ATOMIC_RELEASE,
                         __HIP_MEMORY_SCOPE_AGENT);
      while (__hip_atomic_load(flag, __ATOMIC_ACQUIRE,
                               __HIP_MEMORY_SCOPE_AGENT) < p)
        __builtin_amdgcn_s_sleep(2);
    }
    __syncthreads();
  }
}

// Reduce 32 values across the 32-lane half-wave; lane ks ends with the fully
// reduced value of index ks. (HW-verified R3-R9, absmax=0.)
__device__ __forceinline__ float bfly32(float (&v)[32], const int ks) {
  float a16[16];
#pragma unroll
  for (int j = 0; j < 16; ++j) {
    const float lo = v[j], hi = v[j + 16];
    const float send = (ks & 16) ? lo : hi;
    const float recv = __shfl_xor(send, 16);
    a16[j] = ((ks & 16) ? hi : lo) + recv;
  }
  float a8[8];
#pragma unroll
  for (int j = 0; j < 8; ++j) {
    const float lo = a16[j], hi = a16[j + 8];
    const float send = (ks & 8) ? lo : hi;
    const float recv = __shfl_xor(send, 8);
    a8[j] = ((ks & 8) ? hi : lo) + recv;
  }
  float a4[4];
#pragma unroll
  for (int j = 0; j < 4; ++j) {
    const float lo = a8[j], hi = a8[j + 4];
    const float send = (ks & 4) ? lo : hi;
    const float recv = __shfl_xor(send, 4);
    a4[j] = ((ks & 4) ? hi : lo) + recv;
  }
  float a2[2];
#pragma unroll
  for (int j = 0; j < 2; ++j) {
    const float lo = a4[j], hi = a4[j + 2];
    const float send = (ks & 2) ? lo : hi;
    const float recv = __shfl_xor(send, 2);
    a2[j] = ((ks & 2) ? hi : lo) + recv;
  }
  const float lo = a2[0], hi = a2[1];
  const float send = (ks & 1) ? lo : hi;
  const float recv = __shfl_xor(send, 1);
  return ((ks & 1) ? hi : lo) + recv;
}

// ======================= ENCODER (persistent) =======================
// 128 WGs x 1024 thr. WG owns hcols jh0..jh0+3 (16 gate-rows/matrix).
// Thread tile: 4 batch-rows x 8 gate-rows x ksl32 (k = ksl*4 + j*128).
// L0 and L1's wih1 term FUSED on a single h0[cur] read. VGPR cap 128
// via __launch_bounds__(1024,4); ~100 live regs -> fits, no spill.
__global__ __launch_bounds__(ENT, 4) void enc_kernel(
    const float* __restrict__ x, const float* __restrict__ init_input,
    const float* __restrict__ w_ih0, const float* __restrict__ w_hh0,
    const float* __restrict__ b0, const float* __restrict__ w_ih1,
    const float* __restrict__ w_hh1, const float* __restrict__ b1,
    unsigned* ws) {
  const int wg = blockIdx.x;
  const int tid = threadIdx.x;
  const int jh0 = wg * 4;

  __shared__ __align__(16) float s_whh0[16 * WST];
  __shared__ __align__(16) float s_wih1[16 * WST];
  __shared__ __align__(16) float s_whh1[16 * WST];
  __shared__ __align__(16) float s_gb0[64 * 16];  // [b][q][gate]
  __shared__ __align__(16) float s_gb1[64 * 16];
  __shared__ float s_wih0[16], s_b0[16], s_b1[16];

  for (int i = tid; i < 16 * HH; i += ENT) {
    const int r16 = i >> 9, k = i & 511;
    const int j = (r16 >> 2) * HH + jh0 + (r16 & 3);  // gate=r16>>2, q=r16&3
    s_whh0[r16 * WST + k] = w_hh0[j * HH + k];
    s_wih1[r16 * WST + k] = w_ih1[j * HH + k];
    s_whh1[r16 * WST + k] = w_hh1[j * HH + k];
  }
  if (tid < 16) {
    const int j = (tid >> 2) * HH + jh0 + (tid & 3);
    s_wih0[tid] = w_ih0[j];
    s_b0[tid] = b0[j];
    s_b1[tid] = b1[j];
  }
  {  // zero-init encoder state
    int idx = wg * ENT + tid;  // 0..131071
    if (idx < 2 * BB * HH) {
      (&g_h0[0][0][0])[idx] = 0.f;
      (&g_h1[0][0][0])[idx] = 0.f;
    }
    if (idx < BB * HH) {
      (&g_c0[0][0])[idx] = 0.f;
      (&g_c1[0][0])[idx] = 0.f;
    }
  }
  unsigned phase = 0;
  gridbar(ws, phase);

  const int gg = tid >> 9;           // gate-row half: rows gg*8..gg*8+7
  const int rg = (tid >> 5) & 15;    // 16 row-groups -> rows rg*4..+3
  const int ks = tid & 31;           // K-split 32: k = ks*4 + j*128
  const int b0r = rg * 4;
  const int eb = b0r + (ks >> 3);          // butterfly out: batch row
  const int r16o = gg * 8 + (ks & 7);      // butterfly out: gate-row
  const int eslot = eb * 16 + (r16o & 3) * 4 + (r16o >> 2);  // [b][q][gate]

  for (int tk = 1; tk <= TT + 1; ++tk) {
    const int cur = (tk - 1) & 1, nxt = tk & 1;
    const bool do0 = (tk <= TT), do1 = (tk >= 2);

    float acc0[32], acc1[32];
#pragma unroll
    for (int v = 0; v < 32; ++v) { acc0[v] = 0.f; acc1[v] = 0.f; }

    // ---- fused pass over h0[cur]: L0 (whh0) + L1 wih1-term ----
#pragma unroll
    for (int j = 0; j < 4; ++j) {
      const int k = ks * 4 + j * 128;
      float4 hv[4];
#pragma unroll
      for (int r = 0; r < 4; ++r) hv[r] = *(const float4*)&g_h0[cur][b0r + r][k];
      if (do0) {
#pragma unroll
        for (int g = 0; g < 8; ++g) {
          const float4 wv = *(const float4*)&s_whh0[(gg * 8 + g) * WST + k];
#pragma unroll
          for (int r = 0; r < 4; ++r) {
            acc0[r * 8 + g] = fmaf(hv[r].x, wv.x, acc0[r * 8 + g]);
            acc0[r * 8 + g] = fmaf(hv[r].y, wv.y, acc0[r * 8 + g]);
            acc0[r * 8 + g] = fmaf(hv[r].z, wv.z, acc0[r * 8 + g]);
            acc0[r * 8 + g] = fmaf(hv[r].w, wv.w, acc0[r * 8 + g]);
          }
        }
      }
      if (do1) {
#pragma unroll
        for (int g = 0; g < 8; ++g) {
          const float4 wv = *(const float4*)&s_wih1[(gg * 8 + g) * WST + k];
#pragma unroll
          for (int r = 0; r < 4; ++r) {
            acc1[r * 8 + g] = fmaf(hv[r].x, wv.x, acc1[r * 8 + g]);
            acc1[r * 8 + g] = fmaf(hv[r].y, wv.y, acc1[r * 8 + g]);
            acc1[r * 8 + g] = fmaf(hv[r].z, wv.z, acc1[r * 8 + g]);
            acc1[r * 8 + g] = fmaf(hv[r].w, wv.w, acc1[r * 8 + g]);
          }
        }
      }
    }
    if (do0) {
      float v0 = bfly32(acc0, ks);
      v0 += x[eb * TT + (tk - 1)] * s_wih0[r16o] + s_b0[r16o];
      s_gb0[eslot] = v0;
    }

    if (do1) {  // ---- L1 whh1 term over h1^{tk-2} ----
#pragma unroll
      for (int j = 0; j < 4; ++j) {
        const int k = ks * 4 + j * 128;
        float4 hv[4];
#pragma unroll
        for (int r = 0; r < 4; ++r) hv[r] = *(const float4*)&g_h1[nxt][b0r + r][k];
#pragma unroll
        for (int g = 0; g < 8; ++g) {
          const float4 wv = *(const float4*)&s_whh1[(gg * 8 + g) * WST + k];
#pragma unroll
          for (int r = 0; r < 4; ++r) {
            acc1[r * 8 + g] = fmaf(hv[r].x, wv.x, acc1[r * 8 + g]);
            acc1[r * 8 + g] = fmaf(hv[r].y, wv.y, acc1[r * 8 + g]);
            acc1[r * 8 + g] = fmaf(hv[r].z, wv.z, acc1[r * 8 + g]);
            acc1[r * 8 + g] = fmaf(hv[r].w, wv.w, acc1[r * 8 + g]);
          }
        }
      }
      s_gb1[eslot] = bfly32(acc1, ks) + s_b1[r16o];
    }
    __syncthreads();

    if (do0 && tid < 256) {  // cell0 -> h0^{tk}: 64 b x 4 q
      const int b = tid >> 2, q = tid & 3, jh = jh0 + q;
      const float4 gv = *(const float4*)&s_gb0[b * 16 + q * 4];
      float c = g_c0[b][jh];
      g_h0[nxt][b][jh] = cellupd(gv.x, gv.y, gv.z, gv.w, c);
      g_c0[b][jh] = c;
    }
    if (do1 && tid >= 256 && tid < 512) {  // cell1 -> h1^{tk-1}
      const int t = tid - 256, b = t >> 2, q = t & 3, jh = jh0 + q;
      const float4 gv = *(const float4*)&s_gb1[b * 16 + q * 4];
      float c = g_c1[b][jh];
      g_h1[cur][b][jh] = cellupd(gv.x, gv.y, gv.z, gv.w, c);
      g_c1[b][jh] = c;
    }
    gridbar(ws, phase);
  }

  // ---- expand final states over n_samples: row r = b*16+s ----
  {
    int gt = wg * ENT + tid;         // 0..131071 == RR*HH/4 float4 slots
    int r = gt >> 7, k4 = gt & 127;
    int b = r >> 4;
    ((float4*)&g_H0[0][r][0])[k4] = ((const float4*)&g_h0[0][b][0])[k4];
    ((float4*)&g_C0[r][0])[k4] = ((const float4*)&g_c0[b][0])[k4];
    ((float4*)&g_H1[0][r][0])[k4] = ((const float4*)&g_h1[0][b][0])[k4];
    ((float4*)&g_C1[r][0])[k4] = ((const float4*)&g_c1[b][0])[k4];
    if (gt < RR) g_u[0][gt] = init_input[gt];
  }
}

// ======================= DECODER (per-step GEMM kernels) =======================
// Kernel boundaries = global sync. Grid 256 WGs x 512 thr. CG=bid&15
// (32 hcols), RQ=bid>>4 (64 rows). B rows j = gate*32 + hl (jsrc =
// gate*HH + hcol0 + hl). Thread = txx (1 hcol, ALL 4 gates) x ty (4 rows)
// -> acc[4][4], cell update fully thread-local in epilogue.

__global__ __launch_bounds__(512, 4) void dec_l0(
    const float* __restrict__ w_hh0, const float* __restrict__ w_ih0,
    const float* __restrict__ b0, const float* __restrict__ b_out,
    float* __restrict__ out, int d) {
  __shared__ __align__(16) float As[DM][LSTR];
  __shared__ __align__(16) float Bs[DN][LSTR];
  __shared__ float s_wi[DN], s_bi[DN];
  const int tid = threadIdx.x;
  const int CG = blockIdx.x & 15, RQ = blockIdx.x >> 4;
  const int row0 = RQ * DM;
  const int hcol0 = CG * 32;
  const int txx = tid & 31, ty = tid >> 5;  // hcol, row-group (4 rows)

  if (tid < DN) {  // j = gate*32 + hl
    const int jsrc = (tid >> 5) * HH + hcol0 + (tid & 31);
    s_wi[tid] = w_ih0[jsrc];
    s_bi[tid] = b0[jsrc];
  }

  const int cur = d & 1, nxt = cur ^ 1;
  const int ub = d & 1, nb = ub ^ 1;
  const float* __restrict__ A = &g_H0[cur][0][0];

  float acc[4][4];  // [row][gate]
#pragma unroll
  for (int r = 0; r < 4; ++r)
#pragma unroll
    for (int g = 0; g < 4; ++g) acc[r][g] = 0.f;

  for (int kt = 0; kt < 8; ++kt) {
    const int k0 = kt * DK;
    __syncthreads();
#pragma unroll
    for (int i = 0; i < 2; ++i) {  // stage A [m][k]: 1024 float4
      const int q = tid + i * 512;
      const int m = q >> 4, kk = (q & 15) * 4;
      *(float4*)&As[m][kk] = *(const float4*)&A[(row0 + m) * HH + k0 + kk];
    }
#pragma unroll
    for (int i = 0; i < 4; ++i) {  // stage B [j][k]: 2048 float4
      const int q = tid + i * 512;
      const int j = q >> 4, kk = (q & 15) * 4;
      const int jsrc = (j >> 5) * HH + hcol0 + (j & 31);
      *(float4*)&Bs[j][kk] = *(const float4*)&w_hh0[jsrc * HH + k0 + kk];
    }
    __syncthreads();
#pragma unroll 4
    for (int kc = 0; kc < 16; ++kc) {
      float4 av[4], bv[4];
#pragma unroll
      for (int r = 0; r < 4; ++r) av[r] = *(const float4*)&As[ty * 4 + r][kc * 4];
#pragma unroll
      for (int g = 0; g < 4; ++g) bv[g] = *(const float4*)&Bs[g * 32 + txx][kc * 4];
#pragma unroll
      for (int r = 0; r < 4; ++r)
#pragma unroll
        for (int g = 0; g < 4; ++g) {
          acc[r][g] = fmaf(av[r].x, bv[g].x, acc[r][g]);
          acc[r][g] = fmaf(av[r].y, bv[g].y, acc[r][g]);
          acc[r][g] = fmaf(av[r].z, bv[g].z, acc[r][g]);
          acc[r][g] = fmaf(av[r].w, bv[g].w, acc[r][g]);
        }
    }
  }

  const int hcol = hcol0 + txx;
#pragma unroll
  for (int r = 0; r < 4; ++r) {  // fused cell epilogue (all thread-local)
    const int row = row0 + ty * 4 + r;
    const float u = g_u[ub][row];
    const float iv = acc[r][0] + u * s_wi[0 * 32 + txx] + s_bi[0 * 32 + txx];
    const float fv = acc[r][1] + u * s_wi[1 * 32 + txx] + s_bi[1 * 32 + txx];
    const float gv = acc[r][2] + u * s_wi[2 * 32 + txx] + s_bi[2 * 32 + txx];
    const float ov = acc[r][3] + u * s_wi[3 * 32 + txx] + s_bi[3 * 32 + txx];
    float c = g_C0[row][hcol];
    g_H0[nxt][row][hcol] = cellupd(iv, fv, gv, ov, c);
    g_C0[row][hcol] = c;
  }
  if (CG == 0 && txx == 0) {  // init next-u and out[:,d] with b_out
    const float bo = b_out[0];
#pragma unroll
    for (int r = 0; r < 4; ++r) {
      const int row = row0 + ty * 4 + r;
      g_u[nb][row] = bo;
      out[row * HOR + d] = bo;
    }
  }
}

__global__ __launch_bounds__(512, 4) void dec_l1(
    const float* __restrict__ w_ih1, const float* __restrict__ w_hh1,
    const float* __restrict__ b1, const float* __restrict__ w_out,
    float* __restrict__ out, int d) {
  __shared__ __align__(16) float As[DM][LSTR];
  __shared__ __align__(16) float Bs[DN][LSTR];
  __shared__ float s_bi[DN];
  const int tid = threadIdx.x;
  const int CG = blockIdx.x & 15, RQ = blockIdx.x >> 4;
  const int row0 = RQ * DM;
  const int hcol0 = CG * 32;
  const int txx = tid & 31, ty = tid >> 5;

  if (tid < DN) {
    const int jsrc = (tid >> 5) * HH + hcol0 + (tid & 31);
    s_bi[tid] = b1[jsrc];
  }

  const int cur = d & 1, nxt = cur ^ 1;
  const int nb = (d & 1) ^ 1;
  const int hcol = hcol0 + txx;
  const float wo = w_out[hcol];

  float acc[4][4];
#pragma unroll
  for (int r = 0; r < 4; ++r)
#pragma unroll
    for (int g = 0; g < 4; ++g) acc[r][g] = 0.f;

#pragma unroll
  for (int ph = 0; ph < 2; ++ph) {
    const float* __restrict__ A = ph ? &g_H1[cur][0][0] : &g_H0[nxt][0][0];
    const float* __restrict__ W = ph ? w_hh1 : w_ih1;
    for (int kt = 0; kt < 8; ++kt) {
      const int k0 = kt * DK;
      __syncthreads();
#pragma unroll
      for (int i = 0; i < 2; ++i) {
        const int q = tid + i * 512;
        const int m = q >> 4, kk = (q & 15) * 4;
        *(float4*)&As[m][kk] = *(const float4*)&A[(row0 + m) * HH + k0 + kk];
      }
#pragma unroll
      for (int i = 0; i < 4; ++i) {
        const int q = tid + i * 512;
        const int j = q >> 4, kk = (q & 15) * 4;
        const int jsrc = (j >> 5) * HH + hcol0 + (j & 31);
        *(float4*)&Bs[j][kk] = *(const float4*)&W[jsrc * HH + k0 + kk];
      }
      __syncthreads();
#pragma unroll 4
      for (int kc = 0; kc < 16; ++kc) {
        float4 av[4], bv[4];
#pragma unroll
        for (int r = 0; r < 4; ++r) av[r] = *(const float4*)&As[ty * 4 + r][kc * 4];
#pragma unroll
        for (int g = 0; g < 4; ++g) bv[g] = *(const float4*)&Bs[g * 32 + txx][kc * 4];
#pragma unroll
        for (int r = 0; r < 4; ++r)
#pragma unroll
          for (int g = 0; g < 4; ++g) {
            acc[r][g] = fmaf(av[r].x, bv[g].x, acc[r][g]);
            acc[r][g] = fmaf(av[r].y, bv[g].y, acc[r][g]);
            acc[r][g] = fmaf(av[r].z, bv[g].z, acc[r][g]);
            acc[r][g] = fmaf(av[r].w, bv[g].w, acc[r][g]);
          }
      }
    }
  }

  float pp[4];
#pragma unroll
  for (int r = 0; r < 4; ++r) {  // fused cell epilogue + pred partial
    const int row = row0 + ty * 4 + r;
    const float iv = acc[r][0] + s_bi[0 * 32 + txx];
    const float fv = acc[r][1] + s_bi[1 * 32 + txx];
    const float gv = acc[r][2] + s_bi[2 * 32 + txx];
    const float ov = acc[r][3] + s_bi[3 * 32 + txx];
    float c = g_C1[row][hcol];
    const float h = cellupd(iv, fv, gv, ov, c);
    g_H1[nxt][row][hcol] = h;
    g_C1[row][hcol] = c;
    pp[r] = h * wo;
  }
  // reduce pred partials across the 32 hcol lanes (txx = tid&31)
#pragma unroll
  for (int off = 1; off < 32; off <<= 1) {
#pragma unroll
    for (int r = 0; r < 4; ++r) pp[r] += __shfl_xor(pp[r], off);
  }
  if (txx == 0) {
#pragma unroll
    for (int r = 0; r < 4; ++r) {
      const int row = row0 + ty * 4 + r;
      atomicAdd(&g_u[nb][row], pp[r]);
      atomicAdd(&out[row * HOR + d], pp[r]);
    }
  }
}

extern "C" void kernel_launch(void* const* d_in, const int* in_sizes, int n_in,
                              void* d_out, int out_size, void* d_ws, size_t ws_size,
                              hipStream_t stream) {
  (void)in_sizes; (void)n_in; (void)out_size; (void)ws_size;
  const float* x = (const float*)d_in[0];
  const float* init_input = (const float*)d_in[1];
  const float* w_ih0 = (const float*)d_in[2];
  const float* w_hh0 = (const float*)d_in[3];
  const float* b0 = (const float*)d_in[4];
  const float* w_ih1 = (const float*)d_in[5];
  const float* w_hh1 = (const float*)d_in[6];
  const float* b1 = (const float*)d_in[7];
  const float* w_out = (const float*)d_in[8];
  const float* b_out = (const float*)d_in[9];
  float* out = (float*)d_out;

  hipMemsetAsync(d_ws, 0, (ENW * 32 + 64) * sizeof(unsigned), stream);
  enc_kernel<<<ENW, ENT, 0, stream>>>(x, init_input, w_ih0, w_hh0, b0,
                                      w_ih1, w_hh1, b1, (unsigned*)d_ws);
  for (int d = 0; d < HOR; ++d) {
    dec_l0<<<256, 512, 0, stream>>>(w_hh0, w_ih0, b0, b_out, out, d);
    dec_l1<<<256, 512, 0, stream>>>(w_ih1, w_hh1, b1, w_out, out, d);
  }
}

// Round 11
// 19982.872 us; speedup vs baseline: 1.1144x; 1.1144x over previous
//
#include <hip/hip_runtime.h>
#include <math.h>

// Problem constants (fixed by setup_inputs)
#define BB  64      // batch
#define TT  512     // seq len
#define HH  512     // hidden
#define RR  1024    // decode rows = B*S
#define HOR 64      // horizon
#define WST 520     // encoder LDS weight row stride (floats)

// encoder geometry
#define ENW 128     // encoder WGs (each owns 4 hcols)
#define ENT 1024    // encoder threads/WG

// decoder GEMM tile
#define DM 64       // rows per WG tile
#define DN 128      // gate-cols per WG tile (32 hcols x 4 gates)
#define DK 64       // k tile
#define LSTR 68     // LDS tile row stride (floats): 16B-aligned

// Persistent state in device globals (re-initialized every launch)
__device__ float g_h0[2][BB][HH];
__device__ float g_h1[2][BB][HH];
__device__ float g_c0[BB][HH];
__device__ float g_c1[BB][HH];
__device__ float g_H0[2][RR][HH];
__device__ float g_H1[2][RR][HH];
__device__ float g_C0[RR][HH];
__device__ float g_C1[RR][HH];
__device__ float g_u[2][RR];   // u double-buffer: g_u[d&1] feeds step d

__device__ __forceinline__ float sigf(float v) { return 1.0f / (1.0f + expf(-v)); }

__device__ __forceinline__ float cellupd(float iv, float fv, float gv, float ov, float& c) {
  c = sigf(fv) * c + sigf(iv) * tanhf(gv);
  return sigf(ov) * tanhf(c);
}

// ---- Fence-hoisted tree grid barrier (encoder only) ----
// KEY CHANGE vs R5-R10: spins use RELAXED agent-scope atomics (sc1 loads read
// the coherent point WITHOUT per-poll L2 invalidate); exactly ONE
// __threadfence() (L2 writeback) before arrival and ONE (L2 invalidate) after
// the flag is seen. Previous acquire-spin emitted an L2 invalidate per poll,
// grid-wide, all tick long -- the suspected 28us/tick floor.
// __syncthreads() drains vmcnt for all waves, so tid0's wbl2 publishes the
// whole WG's writes. SAFETY (R2/R4 hangs): 108KB LDS -> 1 WG/CU; 128 WGs vs
// 256 CUs = 2x co-residency slack. Keep it so.
__device__ __forceinline__ void gridbar(unsigned* ws, unsigned& p) {
  __syncthreads();
  ++p;
  const int tid = threadIdx.x;
  unsigned* flag = ws + ENW * 32 + 32;
  if (blockIdx.x == 0) {
    if (tid == 0) {
      __threadfence();  // wbl2: publish this WG's writes to L3
      __hip_atomic_store(ws, p, __ATOMIC_RELAXED, __HIP_MEMORY_SCOPE_AGENT);
    }
    if (tid < ENW) {
      while (__hip_atomic_load(ws + tid * 32, __ATOMIC_RELAXED,
                               __HIP_MEMORY_SCOPE_AGENT) < p)
        __builtin_amdgcn_s_sleep(1);
    }
    __syncthreads();
    if (tid == 0) {
      __hip_atomic_store(flag, p, __ATOMIC_RELAXED, __HIP_MEMORY_SCOPE_AGENT);
      __threadfence();  // inv: subsequent reads see fresh L3 data
    }
  } else {
    if (tid == 0) {
      __threadfence();  // wbl2: publish this WG's writes to L3
      __hip_atomic_store(ws + blockIdx.x * 32, p, __ATOMIC_RELAXED,
                         __HIP_MEMORY_SCOPE_AGENT);
      while (__hip_atomic_load(flag, __ATOMIC_RELAXED,
                               __HIP_MEMORY_SCOPE_AGENT) < p)
        __builtin_amdgcn_s_sleep(2);
      __threadfence();  // inv: subsequent reads see fresh L3 data
    }
  }
  __syncthreads();
}

// Reduce 32 values across the 32-lane half-wave; lane ks ends with the fully
// reduced value of index ks. (HW-verified R3-R10, absmax=0.)
__device__ __forceinline__ float bfly32(float (&v)[32], const int ks) {
  float a16[16];
#pragma unroll
  for (int j = 0; j < 16; ++j) {
    const float lo = v[j], hi = v[j + 16];
    const float send = (ks & 16) ? lo : hi;
    const float recv = __shfl_xor(send, 16);
    a16[j] = ((ks & 16) ? hi : lo) + recv;
  }
  float a8[8];
#pragma unroll
  for (int j = 0; j < 8; ++j) {
    const float lo = a16[j], hi = a16[j + 8];
    const float send = (ks & 8) ? lo : hi;
    const float recv = __shfl_xor(send, 8);
    a8[j] = ((ks & 8) ? hi : lo) + recv;
  }
  float a4[4];
#pragma unroll
  for (int j = 0; j < 4; ++j) {
    const float lo = a8[j], hi = a8[j + 4];
    const float send = (ks & 4) ? lo : hi;
    const float recv = __shfl_xor(send, 4);
    a4[j] = ((ks & 4) ? hi : lo) + recv;
  }
  float a2[2];
#pragma unroll
  for (int j = 0; j < 2; ++j) {
    const float lo = a4[j], hi = a4[j + 2];
    const float send = (ks & 2) ? lo : hi;
    const float recv = __shfl_xor(send, 2);
    a2[j] = ((ks & 2) ? hi : lo) + recv;
  }
  const float lo = a2[0], hi = a2[1];
  const float send = (ks & 1) ? lo : hi;
  const float recv = __shfl_xor(send, 1);
  return ((ks & 1) ? hi : lo) + recv;
}

// ======================= ENCODER (persistent) =======================
// Identical math to R10 (absmax=0): 128 WGs x 1024 thr; WG owns hcols
// jh0..jh0+3; thread tile 4 rows x 8 gate-rows x ks32; L0 + L1-wih1 fused
// on one h0[cur] read. ONLY the barrier changed this round.
__global__ __launch_bounds__(ENT, 4) void enc_kernel(
    const float* __restrict__ x, const float* __restrict__ init_input,
    const float* __restrict__ w_ih0, const float* __restrict__ w_hh0,
    const float* __restrict__ b0, const float* __restrict__ w_ih1,
    const float* __restrict__ w_hh1, const float* __restrict__ b1,
    unsigned* ws) {
  const int wg = blockIdx.x;
  const int tid = threadIdx.x;
  const int jh0 = wg * 4;

  __shared__ __align__(16) float s_whh0[16 * WST];
  __shared__ __align__(16) float s_wih1[16 * WST];
  __shared__ __align__(16) float s_whh1[16 * WST];
  __shared__ __align__(16) float s_gb0[64 * 16];  // [b][q][gate]
  __shared__ __align__(16) float s_gb1[64 * 16];
  __shared__ float s_wih0[16], s_b0[16], s_b1[16];

  for (int i = tid; i < 16 * HH; i += ENT) {
    const int r16 = i >> 9, k = i & 511;
    const int j = (r16 >> 2) * HH + jh0 + (r16 & 3);  // gate=r16>>2, q=r16&3
    s_whh0[r16 * WST + k] = w_hh0[j * HH + k];
    s_wih1[r16 * WST + k] = w_ih1[j * HH + k];
    s_whh1[r16 * WST + k] = w_hh1[j * HH + k];
  }
  if (tid < 16) {
    const int j = (tid >> 2) * HH + jh0 + (tid & 3);
    s_wih0[tid] = w_ih0[j];
    s_b0[tid] = b0[j];
    s_b1[tid] = b1[j];
  }
  {  // zero-init encoder state
    int idx = wg * ENT + tid;  // 0..131071
    if (idx < 2 * BB * HH) {
      (&g_h0[0][0][0])[idx] = 0.f;
      (&g_h1[0][0][0])[idx] = 0.f;
    }
    if (idx < BB * HH) {
      (&g_c0[0][0])[idx] = 0.f;
      (&g_c1[0][0])[idx] = 0.f;
    }
  }
  unsigned phase = 0;
  gridbar(ws, phase);

  const int gg = tid >> 9;           // gate-row half: rows gg*8..gg*8+7
  const int rg = (tid >> 5) & 15;    // 16 row-groups -> rows rg*4..+3
  const int ks = tid & 31;           // K-split 32: k = ks*4 + j*128
  const int b0r = rg * 4;
  const int eb = b0r + (ks >> 3);          // butterfly out: batch row
  const int r16o = gg * 8 + (ks & 7);      // butterfly out: gate-row
  const int eslot = eb * 16 + (r16o & 3) * 4 + (r16o >> 2);  // [b][q][gate]

  for (int tk = 1; tk <= TT + 1; ++tk) {
    const int cur = (tk - 1) & 1, nxt = tk & 1;
    const bool do0 = (tk <= TT), do1 = (tk >= 2);

    float acc0[32], acc1[32];
#pragma unroll
    for (int v = 0; v < 32; ++v) { acc0[v] = 0.f; acc1[v] = 0.f; }

    // ---- fused pass over h0[cur]: L0 (whh0) + L1 wih1-term ----
#pragma unroll
    for (int j = 0; j < 4; ++j) {
      const int k = ks * 4 + j * 128;
      float4 hv[4];
#pragma unroll
      for (int r = 0; r < 4; ++r) hv[r] = *(const float4*)&g_h0[cur][b0r + r][k];
      if (do0) {
#pragma unroll
        for (int g = 0; g < 8; ++g) {
          const float4 wv = *(const float4*)&s_whh0[(gg * 8 + g) * WST + k];
#pragma unroll
          for (int r = 0; r < 4; ++r) {
            acc0[r * 8 + g] = fmaf(hv[r].x, wv.x, acc0[r * 8 + g]);
            acc0[r * 8 + g] = fmaf(hv[r].y, wv.y, acc0[r * 8 + g]);
            acc0[r * 8 + g] = fmaf(hv[r].z, wv.z, acc0[r * 8 + g]);
            acc0[r * 8 + g] = fmaf(hv[r].w, wv.w, acc0[r * 8 + g]);
          }
        }
      }
      if (do1) {
#pragma unroll
        for (int g = 0; g < 8; ++g) {
          const float4 wv = *(const float4*)&s_wih1[(gg * 8 + g) * WST + k];
#pragma unroll
          for (int r = 0; r < 4; ++r) {
            acc1[r * 8 + g] = fmaf(hv[r].x, wv.x, acc1[r * 8 + g]);
            acc1[r * 8 + g] = fmaf(hv[r].y, wv.y, acc1[r * 8 + g]);
            acc1[r * 8 + g] = fmaf(hv[r].z, wv.z, acc1[r * 8 + g]);
            acc1[r * 8 + g] = fmaf(hv[r].w, wv.w, acc1[r * 8 + g]);
          }
        }
      }
    }
    if (do0) {
      float v0 = bfly32(acc0, ks);
      v0 += x[eb * TT + (tk - 1)] * s_wih0[r16o] + s_b0[r16o];
      s_gb0[eslot] = v0;
    }

    if (do1) {  // ---- L1 whh1 term over h1^{tk-2} ----
#pragma unroll
      for (int j = 0; j < 4; ++j) {
        const int k = ks * 4 + j * 128;
        float4 hv[4];
#pragma unroll
        for (int r = 0; r < 4; ++r) hv[r] = *(const float4*)&g_h1[nxt][b0r + r][k];
#pragma unroll
        for (int g = 0; g < 8; ++g) {
          const float4 wv = *(const float4*)&s_whh1[(gg * 8 + g) * WST + k];
#pragma unroll
          for (int r = 0; r < 4; ++r) {
            acc1[r * 8 + g] = fmaf(hv[r].x, wv.x, acc1[r * 8 + g]);
            acc1[r * 8 + g] = fmaf(hv[r].y, wv.y, acc1[r * 8 + g]);
            acc1[r * 8 + g] = fmaf(hv[r].z, wv.z, acc1[r * 8 + g]);
            acc1[r * 8 + g] = fmaf(hv[r].w, wv.w, acc1[r * 8 + g]);
          }
        }
      }
      s_gb1[eslot] = bfly32(acc1, ks) + s_b1[r16o];
    }
    __syncthreads();

    if (do0 && tid < 256) {  // cell0 -> h0^{tk}: 64 b x 4 q
      const int b = tid >> 2, q = tid & 3, jh = jh0 + q;
      const float4 gv = *(const float4*)&s_gb0[b * 16 + q * 4];
      float c = g_c0[b][jh];
      g_h0[nxt][b][jh] = cellupd(gv.x, gv.y, gv.z, gv.w, c);
      g_c0[b][jh] = c;
    }
    if (do1 && tid >= 256 && tid < 512) {  // cell1 -> h1^{tk-1}
      const int t = tid - 256, b = t >> 2, q = t & 3, jh = jh0 + q;
      const float4 gv = *(const float4*)&s_gb1[b * 16 + q * 4];
      float c = g_c1[b][jh];
      g_h1[cur][b][jh] = cellupd(gv.x, gv.y, gv.z, gv.w, c);
      g_c1[b][jh] = c;
    }
    gridbar(ws, phase);
  }

  // ---- expand final states over n_samples: row r = b*16+s ----
  {
    int gt = wg * ENT + tid;         // 0..131071 == RR*HH/4 float4 slots
    int r = gt >> 7, k4 = gt & 127;
    int b = r >> 4;
    ((float4*)&g_H0[0][r][0])[k4] = ((const float4*)&g_h0[0][b][0])[k4];
    ((float4*)&g_C0[r][0])[k4] = ((const float4*)&g_c0[b][0])[k4];
    ((float4*)&g_H1[0][r][0])[k4] = ((const float4*)&g_h1[0][b][0])[k4];
    ((float4*)&g_C1[r][0])[k4] = ((const float4*)&g_c1[b][0])[k4];
    if (gt < RR) g_u[0][gt] = init_input[gt];
  }
}

// ======================= DECODER (per-step GEMM kernels) =======================
// UNCHANGED from R10 (isolate the barrier variable). Kernel boundaries =
// global sync. Grid 256 WGs x 512 thr. CG=bid&15 (32 hcols), RQ=bid>>4
// (64 rows). Thread = txx (1 hcol, ALL 4 gates) x ty (4 rows) -> acc[4][4],
// cell update fully thread-local in epilogue.

__global__ __launch_bounds__(512, 4) void dec_l0(
    const float* __restrict__ w_hh0, const float* __restrict__ w_ih0,
    const float* __restrict__ b0, const float* __restrict__ b_out,
    float* __restrict__ out, int d) {
  __shared__ __align__(16) float As[DM][LSTR];
  __shared__ __align__(16) float Bs[DN][LSTR];
  __shared__ float s_wi[DN], s_bi[DN];
  const int tid = threadIdx.x;
  const int CG = blockIdx.x & 15, RQ = blockIdx.x >> 4;
  const int row0 = RQ * DM;
  const int hcol0 = CG * 32;
  const int txx = tid & 31, ty = tid >> 5;  // hcol, row-group (4 rows)

  if (tid < DN) {  // j = gate*32 + hl
    const int jsrc = (tid >> 5) * HH + hcol0 + (tid & 31);
    s_wi[tid] = w_ih0[jsrc];
    s_bi[tid] = b0[jsrc];
  }

  const int cur = d & 1, nxt = cur ^ 1;
  const int ub = d & 1, nb = ub ^ 1;
  const float* __restrict__ A = &g_H0[cur][0][0];

  float acc[4][4];  // [row][gate]
#pragma unroll
  for (int r = 0; r < 4; ++r)
#pragma unroll
    for (int g = 0; g < 4; ++g) acc[r][g] = 0.f;

  for (int kt = 0; kt < 8; ++kt) {
    const int k0 = kt * DK;
    __syncthreads();
#pragma unroll
    for (int i = 0; i < 2; ++i) {  // stage A [m][k]: 1024 float4
      const int q = tid + i * 512;
      const int m = q >> 4, kk = (q & 15) * 4;
      *(float4*)&As[m][kk] = *(const float4*)&A[(row0 + m) * HH + k0 + kk];
    }
#pragma unroll
    for (int i = 0; i < 4; ++i) {  // stage B [j][k]: 2048 float4
      const int q = tid + i * 512;
      const int j = q >> 4, kk = (q & 15) * 4;
      const int jsrc = (j >> 5) * HH + hcol0 + (j & 31);
      *(float4*)&Bs[j][kk] = *(const float4*)&w_hh0[jsrc * HH + k0 + kk];
    }
    __syncthreads();
#pragma unroll 4
    for (int kc = 0; kc < 16; ++kc) {
      float4 av[4], bv[4];
#pragma unroll
      for (int r = 0; r < 4; ++r) av[r] = *(const float4*)&As[ty * 4 + r][kc * 4];
#pragma unroll
      for (int g = 0; g < 4; ++g) bv[g] = *(const float4*)&Bs[g * 32 + txx][kc * 4];
#pragma unroll
      for (int r = 0; r < 4; ++r)
#pragma unroll
        for (int g = 0; g < 4; ++g) {
          acc[r][g] = fmaf(av[r].x, bv[g].x, acc[r][g]);
          acc[r][g] = fmaf(av[r].y, bv[g].y, acc[r][g]);
          acc[r][g] = fmaf(av[r].z, bv[g].z, acc[r][g]);
          acc[r][g] = fmaf(av[r].w, bv[g].w, acc[r][g]);
        }
    }
  }

  const int hcol = hcol0 + txx;
#pragma unroll
  for (int r = 0; r < 4; ++r) {  // fused cell epilogue (all thread-local)
    const int row = row0 + ty * 4 + r;
    const float u = g_u[ub][row];
    const float iv = acc[r][0] + u * s_wi[0 * 32 + txx] + s_bi[0 * 32 + txx];
    const float fv = acc[r][1] + u * s_wi[1 * 32 + txx] + s_bi[1 * 32 + txx];
    const float gv = acc[r][2] + u * s_wi[2 * 32 + txx] + s_bi[2 * 32 + txx];
    const float ov = acc[r][3] + u * s_wi[3 * 32 + txx] + s_bi[3 * 32 + txx];
    float c = g_C0[row][hcol];
    g_H0[nxt][row][hcol] = cellupd(iv, fv, gv, ov, c);
    g_C0[row][hcol] = c;
  }
  if (CG == 0 && txx == 0) {  // init next-u and out[:,d] with b_out
    const float bo = b_out[0];
#pragma unroll
    for (int r = 0; r < 4; ++r) {
      const int row = row0 + ty * 4 + r;
      g_u[nb][row] = bo;
      out[row * HOR + d] = bo;
    }
  }
}

__global__ __launch_bounds__(512, 4) void dec_l1(
    const float* __restrict__ w_ih1, const float* __restrict__ w_hh1,
    const float* __restrict__ b1, const float* __restrict__ w_out,
    float* __restrict__ out, int d) {
  __shared__ __align__(16) float As[DM][LSTR];
  __shared__ __align__(16) float Bs[DN][LSTR];
  __shared__ float s_bi[DN];
  const int tid = threadIdx.x;
  const int CG = blockIdx.x & 15, RQ = blockIdx.x >> 4;
  const int row0 = RQ * DM;
  const int hcol0 = CG * 32;
  const int txx = tid & 31, ty = tid >> 5;

  if (tid < DN) {
    const int jsrc = (tid >> 5) * HH + hcol0 + (tid & 31);
    s_bi[tid] = b1[jsrc];
  }

  const int cur = d & 1, nxt = cur ^ 1;
  const int nb = (d & 1) ^ 1;
  const int hcol = hcol0 + txx;
  const float wo = w_out[hcol];

  float acc[4][4];
#pragma unroll
  for (int r = 0; r < 4; ++r)
#pragma unroll
    for (int g = 0; g < 4; ++g) acc[r][g] = 0.f;

#pragma unroll
  for (int ph = 0; ph < 2; ++ph) {
    const float* __restrict__ A = ph ? &g_H1[cur][0][0] : &g_H0[nxt][0][0];
    const float* __restrict__ W = ph ? w_hh1 : w_ih1;
    for (int kt = 0; kt < 8; ++kt) {
      const int k0 = kt * DK;
      __syncthreads();
#pragma unroll
      for (int i = 0; i < 2; ++i) {
        const int q = tid + i * 512;
        const int m = q >> 4, kk = (q & 15) * 4;
        *(float4*)&As[m][kk] = *(const float4*)&A[(row0 + m) * HH + k0 + kk];
      }
#pragma unroll
      for (int i = 0; i < 4; ++i) {
        const int q = tid + i * 512;
        const int j = q >> 4, kk = (q & 15) * 4;
        const int jsrc = (j >> 5) * HH + hcol0 + (j & 31);
        *(float4*)&Bs[j][kk] = *(const float4*)&W[jsrc * HH + k0 + kk];
      }
      __syncthreads();
#pragma unroll 4
      for (int kc = 0; kc < 16; ++kc) {
        float4 av[4], bv[4];
#pragma unroll
        for (int r = 0; r < 4; ++r) av[r] = *(const float4*)&As[ty * 4 + r][kc * 4];
#pragma unroll
        for (int g = 0; g < 4; ++g) bv[g] = *(const float4*)&Bs[g * 32 + txx][kc * 4];
#pragma unroll
        for (int r = 0; r < 4; ++r)
#pragma unroll
          for (int g = 0; g < 4; ++g) {
            acc[r][g] = fmaf(av[r].x, bv[g].x, acc[r][g]);
            acc[r][g] = fmaf(av[r].y, bv[g].y, acc[r][g]);
            acc[r][g] = fmaf(av[r].z, bv[g].z, acc[r][g]);
            acc[r][g] = fmaf(av[r].w, bv[g].w, acc[r][g]);
          }
      }
    }
  }

  float pp[4];
#pragma unroll
  for (int r = 0; r < 4; ++r) {  // fused cell epilogue + pred partial
    const int row = row0 + ty * 4 + r;
    const float iv = acc[r][0] + s_bi[0 * 32 + txx];
    const float fv = acc[r][1] + s_bi[1 * 32 + txx];
    const float gv = acc[r][2] + s_bi[2 * 32 + txx];
    const float ov = acc[r][3] + s_bi[3 * 32 + txx];
    float c = g_C1[row][hcol];
    const float h = cellupd(iv, fv, gv, ov, c);
    g_H1[nxt][row][hcol] = h;
    g_C1[row][hcol] = c;
    pp[r] = h * wo;
  }
  // reduce pred partials across the 32 hcol lanes (txx = tid&31)
#pragma unroll
  for (int off = 1; off < 32; off <<= 1) {
#pragma unroll
    for (int r = 0; r < 4; ++r) pp[r] += __shfl_xor(pp[r], off);
  }
  if (txx == 0) {
#pragma unroll
    for (int r = 0; r < 4; ++r) {
      const int row = row0 + ty * 4 + r;
      atomicAdd(&g_u[nb][row], pp[r]);
      atomicAdd(&out[row * HOR + d], pp[r]);
    }
  }
}

extern "C" void kernel_launch(void* const* d_in, const int* in_sizes, int n_in,
                              void* d_out, int out_size, void* d_ws, size_t ws_size,
                              hipStream_t stream) {
  (void)in_sizes; (void)n_in; (void)out_size; (void)ws_size;
  const float* x = (const float*)d_in[0];
  const float* init_input = (const float*)d_in[1];
  const float* w_ih0 = (const float*)d_in[2];
  const float* w_hh0 = (const float*)d_in[3];
  const float* b0 = (const float*)d_in[4];
  const float* w_ih1 = (const float*)d_in[5];
  const float* w_hh1 = (const float*)d_in[6];
  const float* b1 = (const float*)d_in[7];
  const float* w_out = (const float*)d_in[8];
  const float* b_out = (const float*)d_in[9];
  float* out = (float*)d_out;

  hipMemsetAsync(d_ws, 0, (ENW * 32 + 64) * sizeof(unsigned), stream);
  enc_kernel<<<ENW, ENT, 0, stream>>>(x, init_input, w_ih0, w_hh0, b0,
                                      w_ih1, w_hh1, b1, (unsigned*)d_ws);
  for (int d = 0; d < HOR; ++d) {
    dec_l0<<<256, 512, 0, stream>>>(w_hh0, w_ih0, b0, b_out, out, d);
    dec_l1<<<256, 512, 0, stream>>>(w_ih1, w_hh1, b1, w_out, out, d);
  }
}

// Round 12
// 16624.710 us; speedup vs baseline: 1.3395x; 1.2020x over previous
//
#include <hip/hip_runtime.h>
#include <math.h>

// Problem constants (fixed by setup_inputs)
#define BB  64      // batch
#define TT  512     // seq len
#define HH  512     // hidden
#define RR  1024    // decode rows = B*S
#define HOR 64      // horizon
#define WST 520     // encoder LDS weight row stride (floats)

// encoder geometry
#define ENW 128     // encoder WGs (each owns 4 hcols)
#define ENT 1024    // encoder threads/WG

typedef unsigned short ushort;
typedef __attribute__((ext_vector_type(8))) short bf16x8;     // 8 bf16 (4 VGPRs)
typedef __attribute__((ext_vector_type(8))) unsigned short ushort8;
typedef __attribute__((ext_vector_type(4))) float f32x4;

// Persistent state in device globals (re-initialized every launch)
__device__ float g_h0[2][BB][HH];
__device__ float g_h1[2][BB][HH];
__device__ float g_c0[BB][HH];
__device__ float g_c1[BB][HH];
__device__ float g_C0[RR][HH];
__device__ float g_C1[RR][HH];
__device__ float g_u[2][RR];       // u double-buffer: g_u[d&1] feeds step d
// split-bf16 decoder state (hi + lo residual; GEMM A operands)
__device__ ushort H0h[2][RR][HH], H0l[2][RR][HH];
__device__ ushort H1h[2][RR][HH], H1l[2][RR][HH];
// split-bf16 weights (prep kernel, once per launch)
__device__ ushort Whh0h[4 * HH][HH], Whh0l[4 * HH][HH];
__device__ ushort Wih1h[4 * HH][HH], Wih1l[4 * HH][HH];
__device__ ushort Whh1h[4 * HH][HH], Whh1l[4 * HH][HH];

__device__ __forceinline__ float sigf(float v) { return 1.0f / (1.0f + expf(-v)); }

__device__ __forceinline__ float cellupd(float iv, float fv, float gv, float ov, float& c) {
  c = sigf(fv) * c + sigf(iv) * tanhf(gv);
  return sigf(ov) * tanhf(c);
}

// bf16 RNE helpers (manual bit ops; no API ambiguity)
__device__ __forceinline__ ushort f2bf(float x) {
  unsigned u = __float_as_uint(x);
  unsigned r = u + 0x7FFFu + ((u >> 16) & 1u);
  return (ushort)(r >> 16);
}
__device__ __forceinline__ float bf2f(ushort h) {
  return __uint_as_float(((unsigned)h) << 16);
}

// ---- Fence-hoisted tree grid barrier (encoder only; R11-verified) ----
// RELAXED spins (no per-poll L2 invalidate) + ONE __threadfence() before
// arrival / after flag. SAFETY (R2/R4 hangs): 108KB LDS -> 1 WG/CU; 128 WGs
// vs 256 CUs = 2x co-residency slack. Keep it so.
__device__ __forceinline__ void gridbar(unsigned* ws, unsigned& p) {
  __syncthreads();
  ++p;
  const int tid = threadIdx.x;
  unsigned* flag = ws + ENW * 32 + 32;
  if (blockIdx.x == 0) {
    if (tid == 0) {
      __threadfence();
      __hip_atomic_store(ws, p, __ATOMIC_RELAXED, __HIP_MEMORY_SCOPE_AGENT);
    }
    if (tid < ENW) {
      while (__hip_atomic_load(ws + tid * 32, __ATOMIC_RELAXED,
                               __HIP_MEMORY_SCOPE_AGENT) < p)
        __builtin_amdgcn_s_sleep(1);
    }
    __syncthreads();
    if (tid == 0) {
      __hip_atomic_store(flag, p, __ATOMIC_RELAXED, __HIP_MEMORY_SCOPE_AGENT);
      __threadfence();
    }
  } else {
    if (tid == 0) {
      __threadfence();
      __hip_atomic_store(ws + blockIdx.x * 32, p, __ATOMIC_RELAXED,
                         __HIP_MEMORY_SCOPE_AGENT);
      while (__hip_atomic_load(flag, __ATOMIC_RELAXED,
                               __HIP_MEMORY_SCOPE_AGENT) < p)
        __builtin_amdgcn_s_sleep(2);
      __threadfence();
    }
  }
  __syncthreads();
}

// Reduce 32 values across the 32-lane half-wave (HW-verified R3-R11).
__device__ __forceinline__ float bfly32(float (&v)[32], const int ks) {
  float a16[16];
#pragma unroll
  for (int j = 0; j < 16; ++j) {
    const float lo = v[j], hi = v[j + 16];
    const float send = (ks & 16) ? lo : hi;
    const float recv = __shfl_xor(send, 16);
    a16[j] = ((ks & 16) ? hi : lo) + recv;
  }
  float a8[8];
#pragma unroll
  for (int j = 0; j < 8; ++j) {
    const float lo = a16[j], hi = a16[j + 8];
    const float send = (ks & 8) ? lo : hi;
    const float recv = __shfl_xor(send, 8);
    a8[j] = ((ks & 8) ? hi : lo) + recv;
  }
  float a4[4];
#pragma unroll
  for (int j = 0; j < 4; ++j) {
    const float lo = a8[j], hi = a8[j + 4];
    const float send = (ks & 4) ? lo : hi;
    const float recv = __shfl_xor(send, 4);
    a4[j] = ((ks & 4) ? hi : lo) + recv;
  }
  float a2[2];
#pragma unroll
  for (int j = 0; j < 2; ++j) {
    const float lo = a4[j], hi = a4[j + 2];
    const float send = (ks & 2) ? lo : hi;
    const float recv = __shfl_xor(send, 2);
    a2[j] = ((ks & 2) ? hi : lo) + recv;
  }
  const float lo = a2[0], hi = a2[1];
  const float send = (ks & 1) ? lo : hi;
  const float recv = __shfl_xor(send, 1);
  return ((ks & 1) ? hi : lo) + recv;
}

// ======================= PREP: split weights to bf16 hi/lo =======================
__global__ __launch_bounds__(512) void prep_split(
    const float* __restrict__ whh0, const float* __restrict__ wih1,
    const float* __restrict__ whh1) {
  const int i = blockIdx.x * 512 + threadIdx.x;  // grid 2048 -> 1M elements
  float a = whh0[i];
  ushort h = f2bf(a);
  (&Whh0h[0][0])[i] = h;
  (&Whh0l[0][0])[i] = f2bf(a - bf2f(h));
  a = wih1[i];
  h = f2bf(a);
  (&Wih1h[0][0])[i] = h;
  (&Wih1l[0][0])[i] = f2bf(a - bf2f(h));
  a = whh1[i];
  h = f2bf(a);
  (&Whh1h[0][0])[i] = h;
  (&Whh1l[0][0])[i] = f2bf(a - bf2f(h));
}

// ======================= ENCODER (persistent; R11 math, absmax=0) =======================
__global__ __launch_bounds__(ENT, 4) void enc_kernel(
    const float* __restrict__ x, const float* __restrict__ init_input,
    const float* __restrict__ w_ih0, const float* __restrict__ w_hh0,
    const float* __restrict__ b0, const float* __restrict__ w_ih1,
    const float* __restrict__ w_hh1, const float* __restrict__ b1,
    unsigned* ws) {
  const int wg = blockIdx.x;
  const int tid = threadIdx.x;
  const int jh0 = wg * 4;

  __shared__ __align__(16) float s_whh0[16 * WST];
  __shared__ __align__(16) float s_wih1[16 * WST];
  __shared__ __align__(16) float s_whh1[16 * WST];
  __shared__ __align__(16) float s_gb0[64 * 16];  // [b][q][gate]
  __shared__ __align__(16) float s_gb1[64 * 16];
  __shared__ float s_wih0[16], s_b0[16], s_b1[16];

  for (int i = tid; i < 16 * HH; i += ENT) {
    const int r16 = i >> 9, k = i & 511;
    const int j = (r16 >> 2) * HH + jh0 + (r16 & 3);
    s_whh0[r16 * WST + k] = w_hh0[j * HH + k];
    s_wih1[r16 * WST + k] = w_ih1[j * HH + k];
    s_whh1[r16 * WST + k] = w_hh1[j * HH + k];
  }
  if (tid < 16) {
    const int j = (tid >> 2) * HH + jh0 + (tid & 3);
    s_wih0[tid] = w_ih0[j];
    s_b0[tid] = b0[j];
    s_b1[tid] = b1[j];
  }
  {  // zero-init encoder state
    int idx = wg * ENT + tid;
    if (idx < 2 * BB * HH) {
      (&g_h0[0][0][0])[idx] = 0.f;
      (&g_h1[0][0][0])[idx] = 0.f;
    }
    if (idx < BB * HH) {
      (&g_c0[0][0])[idx] = 0.f;
      (&g_c1[0][0])[idx] = 0.f;
    }
  }
  unsigned phase = 0;
  gridbar(ws, phase);

  const int gg = tid >> 9;
  const int rg = (tid >> 5) & 15;
  const int ks = tid & 31;
  const int b0r = rg * 4;
  const int eb = b0r + (ks >> 3);
  const int r16o = gg * 8 + (ks & 7);
  const int eslot = eb * 16 + (r16o & 3) * 4 + (r16o >> 2);

  for (int tk = 1; tk <= TT + 1; ++tk) {
    const int cur = (tk - 1) & 1, nxt = tk & 1;
    const bool do0 = (tk <= TT), do1 = (tk >= 2);

    float acc0[32], acc1[32];
#pragma unroll
    for (int v = 0; v < 32; ++v) { acc0[v] = 0.f; acc1[v] = 0.f; }

#pragma unroll
    for (int j = 0; j < 4; ++j) {
      const int k = ks * 4 + j * 128;
      float4 hv[4];
#pragma unroll
      for (int r = 0; r < 4; ++r) hv[r] = *(const float4*)&g_h0[cur][b0r + r][k];
      if (do0) {
#pragma unroll
        for (int g = 0; g < 8; ++g) {
          const float4 wv = *(const float4*)&s_whh0[(gg * 8 + g) * WST + k];
#pragma unroll
          for (int r = 0; r < 4; ++r) {
            acc0[r * 8 + g] = fmaf(hv[r].x, wv.x, acc0[r * 8 + g]);
            acc0[r * 8 + g] = fmaf(hv[r].y, wv.y, acc0[r * 8 + g]);
            acc0[r * 8 + g] = fmaf(hv[r].z, wv.z, acc0[r * 8 + g]);
            acc0[r * 8 + g] = fmaf(hv[r].w, wv.w, acc0[r * 8 + g]);
          }
        }
      }
      if (do1) {
#pragma unroll
        for (int g = 0; g < 8; ++g) {
          const float4 wv = *(const float4*)&s_wih1[(gg * 8 + g) * WST + k];
#pragma unroll
          for (int r = 0; r < 4; ++r) {
            acc1[r * 8 + g] = fmaf(hv[r].x, wv.x, acc1[r * 8 + g]);
            acc1[r * 8 + g] = fmaf(hv[r].y, wv.y, acc1[r * 8 + g]);
            acc1[r * 8 + g] = fmaf(hv[r].z, wv.z, acc1[r * 8 + g]);
            acc1[r * 8 + g] = fmaf(hv[r].w, wv.w, acc1[r * 8 + g]);
          }
        }
      }
    }
    if (do0) {
      float v0 = bfly32(acc0, ks);
      v0 += x[eb * TT + (tk - 1)] * s_wih0[r16o] + s_b0[r16o];
      s_gb0[eslot] = v0;
    }

    if (do1) {
#pragma unroll
      for (int j = 0; j < 4; ++j) {
        const int k = ks * 4 + j * 128;
        float4 hv[4];
#pragma unroll
        for (int r = 0; r < 4; ++r) hv[r] = *(const float4*)&g_h1[nxt][b0r + r][k];
#pragma unroll
        for (int g = 0; g < 8; ++g) {
          const float4 wv = *(const float4*)&s_whh1[(gg * 8 + g) * WST + k];
#pragma unroll
          for (int r = 0; r < 4; ++r) {
            acc1[r * 8 + g] = fmaf(hv[r].x, wv.x, acc1[r * 8 + g]);
            acc1[r * 8 + g] = fmaf(hv[r].y, wv.y, acc1[r * 8 + g]);
            acc1[r * 8 + g] = fmaf(hv[r].z, wv.z, acc1[r * 8 + g]);
            acc1[r * 8 + g] = fmaf(hv[r].w, wv.w, acc1[r * 8 + g]);
          }
        }
      }
      s_gb1[eslot] = bfly32(acc1, ks) + s_b1[r16o];
    }
    __syncthreads();

    if (do0 && tid < 256) {  // cell0 -> h0^{tk}
      const int b = tid >> 2, q = tid & 3, jh = jh0 + q;
      const float4 gv = *(const float4*)&s_gb0[b * 16 + q * 4];
      float c = g_c0[b][jh];
      g_h0[nxt][b][jh] = cellupd(gv.x, gv.y, gv.z, gv.w, c);
      g_c0[b][jh] = c;
    }
    if (do1 && tid >= 256 && tid < 512) {  // cell1 -> h1^{tk-1}
      const int t = tid - 256, b = t >> 2, q = t & 3, jh = jh0 + q;
      const float4 gv = *(const float4*)&s_gb1[b * 16 + q * 4];
      float c = g_c1[b][jh];
      g_h1[cur][b][jh] = cellupd(gv.x, gv.y, gv.z, gv.w, c);
      g_c1[b][jh] = c;
    }
    gridbar(ws, phase);
  }

  // ---- expand final states over n_samples: row r = b*16+s; emit bf16 hi/lo ----
  {
    int gt = wg * ENT + tid;         // 0..131071 == RR*HH/4 float4 slots
    int r = gt >> 7, k4 = gt & 127;
    int b = r >> 4;
    const float4 h0v = ((const float4*)&g_h0[0][b][0])[k4];
    const float4 h1v = ((const float4*)&g_h1[0][b][0])[k4];
    ((float4*)&g_C0[r][0])[k4] = ((const float4*)&g_c0[b][0])[k4];
    ((float4*)&g_C1[r][0])[k4] = ((const float4*)&g_c1[b][0])[k4];
    const int kb = k4 * 4;
    const float e0[4] = {h0v.x, h0v.y, h0v.z, h0v.w};
    const float e1[4] = {h1v.x, h1v.y, h1v.z, h1v.w};
#pragma unroll
    for (int j = 0; j < 4; ++j) {
      ushort hh = f2bf(e0[j]);
      H0h[0][r][kb + j] = hh;
      H0l[0][r][kb + j] = f2bf(e0[j] - bf2f(hh));
      hh = f2bf(e1[j]);
      H1h[0][r][kb + j] = hh;
      H1l[0][r][kb + j] = f2bf(e1[j] - bf2f(hh));
    }
    if (gt < RR) g_u[0][gt] = init_input[gt];
  }
}

// ======================= DECODER (split-bf16 MFMA GEMMs) =======================
// Grid 256 = CG(16: 32 hcols) x RQ(16: 64 rows); 512 thr = 8 waves:
// wm = wave&3 (rows wm*16), wn = wave>>2 (hcols wn*16). Per wave: one 16-row
// m-tile x 4 gate n-tiles (N arranged [gate][16 hcols] so lane owns all 4
// gates of hcol l&15 at rows (l>>4)*4+r -> thread-local fused cell).
// mfma_f32_16x16x32_bf16; 3-term split per K=32 chunk. A/B staged [row][k]
// k-contiguous: both frags read 8 k's at (lane>>4)*8 -- identical k-grouping
// for A and B, so any internal K-permutation cancels.

__global__ __launch_bounds__(512, 4) void dec_l0(
    const float* __restrict__ w_ih0, const float* __restrict__ b0,
    const float* __restrict__ b_out, float* __restrict__ out, int d) {
  __shared__ __align__(16) ushort Ah[64][72], Al[64][72];
  __shared__ __align__(16) ushort Bh[128][72], Bl[128][72];
  __shared__ float s_wi[128], s_bi[128];
  const int tid = threadIdx.x;
  const int CG = blockIdx.x & 15, RQ = blockIdx.x >> 4;
  const int row0 = RQ * 64, hcol0 = CG * 32;
  const int lane = tid & 63, wv = tid >> 6;
  const int wm = wv & 3, wn = wv >> 2;
  const int mr = lane & 15, kg = lane >> 4;

  if (tid < 128) {  // j2 = g*32+hl -> jsrc = g*HH + hcol0 + hl
    const int jsrc = (tid >> 5) * HH + hcol0 + (tid & 31);
    s_wi[tid] = w_ih0[jsrc];
    s_bi[tid] = b0[jsrc];
  }

  const int cur = d & 1, nxt = cur ^ 1;
  const ushort* __restrict__ Ahg = &H0h[cur][0][0];
  const ushort* __restrict__ Alg = &H0l[cur][0][0];

  f32x4 acc[4];
#pragma unroll
  for (int g = 0; g < 4; ++g) acc[g] = (f32x4){0.f, 0.f, 0.f, 0.f};

  for (int kt = 0; kt < 8; ++kt) {
    const int k0 = kt * 64;
    __syncthreads();
    {  // stage A 64x64 (hi,lo): one ushort8 per thread per array
      const int m = tid >> 3, kk = (tid & 7) * 8;
      *(ushort8*)&Ah[m][kk] = *(const ushort8*)&Ahg[(row0 + m) * HH + k0 + kk];
      *(ushort8*)&Al[m][kk] = *(const ushort8*)&Alg[(row0 + m) * HH + k0 + kk];
    }
#pragma unroll
    for (int i = 0; i < 2; ++i) {  // stage B 128x64 (hi,lo)
      const int q = i * 512 + tid;
      const int j2 = q >> 3, kk = (q & 7) * 8;
      const int jsrc = (j2 >> 5) * HH + hcol0 + (j2 & 31);
      *(ushort8*)&Bh[j2][kk] = *(const ushort8*)&Whh0h[jsrc][k0 + kk];
      *(ushort8*)&Bl[j2][kk] = *(const ushort8*)&Whh0l[jsrc][k0 + kk];
    }
    __syncthreads();
#pragma unroll
    for (int ks2 = 0; ks2 < 2; ++ks2) {
      const int ko = ks2 * 32 + kg * 8;
      const bf16x8 ah = *(const bf16x8*)&Ah[wm * 16 + mr][ko];
      const bf16x8 al = *(const bf16x8*)&Al[wm * 16 + mr][ko];
#pragma unroll
      for (int g = 0; g < 4; ++g) {
        const bf16x8 bh = *(const bf16x8*)&Bh[g * 32 + wn * 16 + mr][ko];
        const bf16x8 bl = *(const bf16x8*)&Bl[g * 32 + wn * 16 + mr][ko];
        acc[g] = __builtin_amdgcn_mfma_f32_16x16x32_bf16(ah, bh, acc[g], 0, 0, 0);
        acc[g] = __builtin_amdgcn_mfma_f32_16x16x32_bf16(ah, bl, acc[g], 0, 0, 0);
        acc[g] = __builtin_amdgcn_mfma_f32_16x16x32_bf16(al, bh, acc[g], 0, 0, 0);
      }
    }
  }

  const int hl2 = wn * 16 + mr;        // local hcol 0..31
  const int hcol = hcol0 + hl2;
  const int ub = d & 1, nb = ub ^ 1;
  const float bo = b_out[0];
#pragma unroll
  for (int r = 0; r < 4; ++r) {  // fused cell epilogue
    const int row = row0 + wm * 16 + kg * 4 + r;
    const float u = g_u[ub][row];
    const float iv = acc[0][r] + u * s_wi[hl2] + s_bi[hl2];
    const float fv = acc[1][r] + u * s_wi[32 + hl2] + s_bi[32 + hl2];
    const float gv = acc[2][r] + u * s_wi[64 + hl2] + s_bi[64 + hl2];
    const float ov = acc[3][r] + u * s_wi[96 + hl2] + s_bi[96 + hl2];
    float c = g_C0[row][hcol];
    const float h = cellupd(iv, fv, gv, ov, c);
    g_C0[row][hcol] = c;
    const ushort hh = f2bf(h);
    H0h[nxt][row][hcol] = hh;
    H0l[nxt][row][hcol] = f2bf(h - bf2f(hh));
    if (CG == 0 && wn == 0 && mr == 0) {  // init next-u and out[:,d]
      g_u[nb][row] = bo;
      out[row * HOR + d] = bo;
    }
  }
}

__global__ __launch_bounds__(512, 4) void dec_l1(
    const float* __restrict__ b1, const float* __restrict__ w_out,
    float* __restrict__ out, int d) {
  __shared__ __align__(16) ushort Ah[64][72], Al[64][72];
  __shared__ __align__(16) ushort Bh[128][72], Bl[128][72];
  __shared__ float s_bi[128];
  const int tid = threadIdx.x;
  const int CG = blockIdx.x & 15, RQ = blockIdx.x >> 4;
  const int row0 = RQ * 64, hcol0 = CG * 32;
  const int lane = tid & 63, wv = tid >> 6;
  const int wm = wv & 3, wn = wv >> 2;
  const int mr = lane & 15, kg = lane >> 4;

  if (tid < 128) {
    const int jsrc = (tid >> 5) * HH + hcol0 + (tid & 31);
    s_bi[tid] = b1[jsrc];
  }

  const int cur = d & 1, nxt = cur ^ 1;

  f32x4 acc[4];
#pragma unroll
  for (int g = 0; g < 4; ++g) acc[g] = (f32x4){0.f, 0.f, 0.f, 0.f};

#pragma unroll
  for (int src = 0; src < 2; ++src) {
    const ushort* __restrict__ Ahg = src ? &H1h[cur][0][0] : &H0h[nxt][0][0];
    const ushort* __restrict__ Alg = src ? &H1l[cur][0][0] : &H0l[nxt][0][0];
    const ushort* __restrict__ Bhg = src ? &Whh1h[0][0] : &Wih1h[0][0];
    const ushort* __restrict__ Blg = src ? &Whh1l[0][0] : &Wih1l[0][0];
    for (int kt = 0; kt < 8; ++kt) {
      const int k0 = kt * 64;
      __syncthreads();
      {
        const int m = tid >> 3, kk = (tid & 7) * 8;
        *(ushort8*)&Ah[m][kk] = *(const ushort8*)&Ahg[(row0 + m) * HH + k0 + kk];
        *(ushort8*)&Al[m][kk] = *(const ushort8*)&Alg[(row0 + m) * HH + k0 + kk];
      }
#pragma unroll
      for (int i = 0; i < 2; ++i) {
        const int q = i * 512 + tid;
        const int j2 = q >> 3, kk = (q & 7) * 8;
        const int jsrc = (j2 >> 5) * HH + hcol0 + (j2 & 31);
        *(ushort8*)&Bh[j2][kk] = *(const ushort8*)&Bhg[jsrc * HH + k0 + kk];
        *(ushort8*)&Bl[j2][kk] = *(const ushort8*)&Blg[jsrc * HH + k0 + kk];
      }
      __syncthreads();
#pragma unroll
      for (int ks2 = 0; ks2 < 2; ++ks2) {
        const int ko = ks2 * 32 + kg * 8;
        const bf16x8 ah = *(const bf16x8*)&Ah[wm * 16 + mr][ko];
        const bf16x8 al = *(const bf16x8*)&Al[wm * 16 + mr][ko];
#pragma unroll
        for (int g = 0; g < 4; ++g) {
          const bf16x8 bh = *(const bf16x8*)&Bh[g * 32 + wn * 16 + mr][ko];
          const bf16x8 bl = *(const bf16x8*)&Bl[g * 32 + wn * 16 + mr][ko];
          acc[g] = __builtin_amdgcn_mfma_f32_16x16x32_bf16(ah, bh, acc[g], 0, 0, 0);
          acc[g] = __builtin_amdgcn_mfma_f32_16x16x32_bf16(ah, bl, acc[g], 0, 0, 0);
          acc[g] = __builtin_amdgcn_mfma_f32_16x16x32_bf16(al, bh, acc[g], 0, 0, 0);
        }
      }
    }
  }

  const int hl2 = wn * 16 + mr;
  const int hcol = hcol0 + hl2;
  const int nb = (d & 1) ^ 1;
  const float wo = w_out[hcol];
  float pp[4];
#pragma unroll
  for (int r = 0; r < 4; ++r) {  // fused cell epilogue + pred partial
    const int row = row0 + wm * 16 + kg * 4 + r;
    const float iv = acc[0][r] + s_bi[hl2];
    const float fv = acc[1][r] + s_bi[32 + hl2];
    const float gv = acc[2][r] + s_bi[64 + hl2];
    const float ov = acc[3][r] + s_bi[96 + hl2];
    float c = g_C1[row][hcol];
    const float h = cellupd(iv, fv, gv, ov, c);
    g_C1[row][hcol] = c;
    const ushort hh = f2bf(h);
    H1h[nxt][row][hcol] = hh;
    H1l[nxt][row][hcol] = f2bf(h - bf2f(hh));
    pp[r] = h * wo;
  }
  // reduce pred partials across the 16 mr lanes (same rows per kg group)
#pragma unroll
  for (int off = 1; off < 16; off <<= 1) {
#pragma unroll
    for (int r = 0; r < 4; ++r) pp[r] += __shfl_xor(pp[r], off);
  }
  if (mr == 0) {
#pragma unroll
    for (int r = 0; r < 4; ++r) {
      const int row = row0 + wm * 16 + kg * 4 + r;
      atomicAdd(&g_u[nb][row], pp[r]);
      atomicAdd(&out[row * HOR + d], pp[r]);
    }
  }
}

extern "C" void kernel_launch(void* const* d_in, const int* in_sizes, int n_in,
                              void* d_out, int out_size, void* d_ws, size_t ws_size,
                              hipStream_t stream) {
  (void)in_sizes; (void)n_in; (void)out_size; (void)ws_size;
  const float* x = (const float*)d_in[0];
  const float* init_input = (const float*)d_in[1];
  const float* w_ih0 = (const float*)d_in[2];
  const float* w_hh0 = (const float*)d_in[3];
  const float* b0 = (const float*)d_in[4];
  const float* w_ih1 = (const float*)d_in[5];
  const float* w_hh1 = (const float*)d_in[6];
  const float* b1 = (const float*)d_in[7];
  const float* w_out = (const float*)d_in[8];
  const float* b_out = (const float*)d_in[9];
  float* out = (float*)d_out;

  hipMemsetAsync(d_ws, 0, (ENW * 32 + 64) * sizeof(unsigned), stream);
  prep_split<<<2048, 512, 0, stream>>>(w_hh0, w_ih1, w_hh1);
  enc_kernel<<<ENW, ENT, 0, stream>>>(x, init_input, w_ih0, w_hh0, b0,
                                      w_ih1, w_hh1, b1, (unsigned*)d_ws);
  for (int d = 0; d < HOR; ++d) {
    dec_l0<<<256, 512, 0, stream>>>(w_ih0, b0, b_out, out, d);
    dec_l1<<<256, 512, 0, stream>>>(b1, w_out, out, d);
  }
}